// Round 1
// baseline (1286.853 us; speedup 1.0000x reference)
//
#include <hip/hip_runtime.h>
#include <hip/hip_bf16.h>

// ---------------------------------------------------------------------------
// GNN forward on MI355X. Strategy:
//  * all matmuls via mfma_f32_16x16x32_bf16 with 3-term split-bf16 (fp32-ish
//    precision at ~830 TF effective ceiling)
//  * one fused kernel per message-passing phase: gather -> redux MLP -> node MLP
//  * activations live in 2 fp32 LDS buffers (C = cur, S = residual sum)
//  * weights pre-split into fragment-ordered bf16 hi/lo arrays in d_ws
// ---------------------------------------------------------------------------

#define H        128
#define FEAT     32
#define M_NODES  32768
#define L_LAYERS 16
#define MU_      (M_NODES / 2)
#define N_TOTAL  (M_NODES * L_LAYERS)

typedef __bf16 bf16x8 __attribute__((ext_vector_type(8)));
typedef float  f32x4  __attribute__((ext_vector_type(4)));

// frag-pair slots in d_ws. One frag-pair = 2 KB = 1024 __bf16 (512 hi, 512 lo).
// frag-pair(ct,kt) lane l holds W[ct*16+(l&15)][kt*32+(l>>4)*8 + j], j=0..7.
#define SLOT_MPU(l) ((l) * 32)        // 5 layers, K=128 (8ct x 4kt)
#define SLOT_MPB0   160               // K=256 (8ct x 8kt)
#define SLOT_MPB(l) (224 + (l) * 32)  // 4 layers, K=128
#define SLOT_NE0    352               // K=256
#define SLOT_NE(l)  (416 + (l) * 32)  // 4 layers, K=128
#define TOTAL_FP    544

// ---------------------------------------------------------------------------
__global__ void prep_kernel(__bf16* __restrict__ frags,
                            const float* __restrict__ mpu_w,
                            const float* __restrict__ mpb0_w,
                            const float* __restrict__ mpb_w,
                            const float* __restrict__ ne0_w,
                            const float* __restrict__ ne_w) {
  int fp = blockIdx.x * 4 + (threadIdx.x >> 6);
  if (fp >= TOTAL_FP) return;
  int lane = threadIdx.x & 63;
  const float* src; int K; int idx;
  if (fp < 160)      { src = mpu_w + (fp >> 5) * H * H;         K = H;     idx = fp & 31; }
  else if (fp < 224) { src = mpb0_w;                            K = 2 * H; idx = fp - 160; }
  else if (fp < 352) { src = mpb_w + ((fp - 224) >> 5) * H * H; K = H;     idx = (fp - 224) & 31; }
  else if (fp < 416) { src = ne0_w;                             K = 2 * H; idx = fp - 352; }
  else               { src = ne_w + ((fp - 416) >> 5) * H * H;  K = H;     idx = (fp - 416) & 31; }
  int KT = K >> 5;
  int ct = idx / KT, kt = idx - ct * KT;
  int col = ct * 16 + (lane & 15);
  int k0  = kt * 32 + (lane >> 4) * 8;
  __bf16* dhi = frags + ((size_t)fp << 10) + lane * 8;
#pragma unroll
  for (int j = 0; j < 8; ++j) {
    float x  = src[col * K + k0 + j];
    __bf16 h = (__bf16)x;
    dhi[j]       = h;
    dhi[512 + j] = (__bf16)(x - (float)h);
  }
}

// ---------------------------------------------------------------------------
__global__ void embed_kernel(float* __restrict__ E,
                             const float* __restrict__ feats,
                             const float* __restrict__ emb_w,
                             const float* __restrict__ emb_b) {
  __shared__ float fl[64][36];
  int tid = threadIdx.x;
  size_t rbase = (size_t)blockIdx.x * 64;
  // stage 64 x 32 feats (512 float4)
  {
    int idx = tid;
#pragma unroll
    for (int rep = 0; rep < 2; ++rep, idx += 256) {
      int r = idx >> 3, c4 = idx & 7;
      *(f32x4*)&fl[r][c4 * 4] = *(const f32x4*)(feats + (rbase + r) * FEAT + c4 * 4);
    }
  }
  __syncthreads();
  int o = tid & 127, rh = tid >> 7;
  float w[32];
#pragma unroll
  for (int i = 0; i < 8; ++i) {
    f32x4 v = *(const f32x4*)(emb_w + o * FEAT + i * 4);
    w[i * 4 + 0] = v[0]; w[i * 4 + 1] = v[1]; w[i * 4 + 2] = v[2]; w[i * 4 + 3] = v[3];
  }
  float b = emb_b[o];
  for (int i = 0; i < 32; ++i) {
    int r = rh * 32 + i;
    float acc = b;
#pragma unroll
    for (int k4 = 0; k4 < 8; ++k4) {
      f32x4 f = *(const f32x4*)&fl[r][k4 * 4];
      acc += f[0] * w[k4 * 4] + f[1] * w[k4 * 4 + 1] + f[2] * w[k4 * 4 + 2] + f[3] * w[k4 * 4 + 3];
    }
    E[(rbase + r) * H + o] = fmaxf(acc, 0.f);
  }
}

// ---------------------------------------------------------------------------
__device__ __forceinline__ void zero_acc(f32x4 (&acc)[4][4]) {
  f32x4 z = {0.f, 0.f, 0.f, 0.f};
#pragma unroll
  for (int a = 0; a < 4; ++a)
#pragma unroll
    for (int b = 0; b < 4; ++b) acc[a][b] = z;
}

// One K=128 GEMM pass: acc += split3( IN[wave rows] @ W_slot[:, ktoff*32 .. ]^T )
__device__ __forceinline__ void gemm_pass(f32x4 (&acc)[4][4], const float (*IN)[132],
                                          const __bf16* __restrict__ frags, int slot, int KT,
                                          int ktoff, int wr, int wc, int lane) {
  bf16x8 whi[4][4], wlo[4][4];
#pragma unroll
  for (int ct = 0; ct < 4; ++ct) {
#pragma unroll
    for (int kt = 0; kt < 4; ++kt) {
      int fpi = (wc * 4 + ct) * KT + (ktoff + kt);
      const __bf16* fb = frags + (((size_t)(slot + fpi)) << 10) + lane * 8;
      whi[ct][kt] = *(const bf16x8*)fb;
      wlo[ct][kt] = *(const bf16x8*)(fb + 512);
    }
  }
  int r16 = lane & 15;
  int k8  = (lane >> 4) * 8;
#pragma unroll
  for (int rt = 0; rt < 4; ++rt) {
    int row = wr * 64 + rt * 16 + r16;
    bf16x8 ahi[4], alo[4];
#pragma unroll
    for (int kt = 0; kt < 4; ++kt) {
      const float* p = &IN[row][kt * 32 + k8];
      f32x4 f0 = *(const f32x4*)p;
      f32x4 f1 = *(const f32x4*)(p + 4);
#pragma unroll
      for (int j = 0; j < 4; ++j) {
        float x = f0[j]; __bf16 h = (__bf16)x;
        ahi[kt][j] = h; alo[kt][j] = (__bf16)(x - (float)h);
      }
#pragma unroll
      for (int j = 0; j < 4; ++j) {
        float x = f1[j]; __bf16 h = (__bf16)x;
        ahi[kt][4 + j] = h; alo[kt][4 + j] = (__bf16)(x - (float)h);
      }
    }
    // three split terms; iterate term-outermost so consecutive MFMAs hit
    // different accumulators (no dependent back-to-back MFMA)
#pragma unroll
    for (int ct = 0; ct < 4; ++ct)
#pragma unroll
      for (int kt = 0; kt < 4; ++kt)
        acc[rt][ct] = __builtin_amdgcn_mfma_f32_16x16x32_bf16(ahi[kt], whi[ct][kt], acc[rt][ct], 0, 0, 0);
#pragma unroll
    for (int ct = 0; ct < 4; ++ct)
#pragma unroll
      for (int kt = 0; kt < 4; ++kt)
        acc[rt][ct] = __builtin_amdgcn_mfma_f32_16x16x32_bf16(ahi[kt], wlo[ct][kt], acc[rt][ct], 0, 0, 0);
#pragma unroll
    for (int ct = 0; ct < 4; ++ct)
#pragma unroll
      for (int kt = 0; kt < 4; ++kt)
        acc[rt][ct] = __builtin_amdgcn_mfma_f32_16x16x32_bf16(alo[kt], whi[ct][kt], acc[rt][ct], 0, 0, 0);
  }
}

// mode 0: C = relu(acc+b)
// mode 1: old = C; C = relu(acc+b); S = C + old   (residual bookkeeping)
// mode 2: global store only
__device__ __forceinline__ void epilogue(const f32x4 (&acc)[4][4], const float* __restrict__ bias,
                                         float (*Cb)[132], float (*Sb)[132], int mode,
                                         float* __restrict__ Eout, int wr, int wc, int lane) {
  int c16 = lane & 15, g4 = (lane >> 4) * 4;
#pragma unroll
  for (int ct = 0; ct < 4; ++ct) {
    int col = wc * 64 + ct * 16 + c16;
    float b = bias[col];
#pragma unroll
    for (int rt = 0; rt < 4; ++rt) {
#pragma unroll
      for (int j = 0; j < 4; ++j) {
        int row = wr * 64 + rt * 16 + g4 + j;
        float v = fmaxf(acc[rt][ct][j] + b, 0.f);
        if (mode == 0) {
          Cb[row][col] = v;
        } else if (mode == 1) {
          float old = Cb[row][col];   // own cell: safe read-then-write
          Cb[row][col] = v;
          Sb[row][col] = v + old;
        } else {
          Eout[(size_t)row * H + col] = v;
        }
      }
    }
  }
}

// ---------------------------------------------------------------------------
__global__ __launch_bounds__(256, 1) void phase_kernel(
    float* __restrict__ E, const int* __restrict__ parents, const __bf16* __restrict__ frags,
    const float* __restrict__ mpu_b, const float* __restrict__ mpb0_b,
    const float* __restrict__ mpb_b, const float* __restrict__ ne0_b,
    const float* __restrict__ ne_b, int s) {
  __shared__ float Cb[128][132];
  __shared__ float Sb[128][132];
  int t = blockIdx.x;
  bool un = t < (MU_ / 128);
  int row0 = t * 128;
  int tid = threadIdx.x;
  int lane = tid & 63, wave = tid >> 6;
  int wr = wave >> 1, wc = wave & 1;

  // ---- stage gathered message rows ----
  {
    int r4 = tid >> 2;
    int cc = (tid & 3) * 8;
#pragma unroll
    for (int rep = 0; rep < 2; ++rep) {
      int row = rep * 64 + r4;
      int gr  = s + row0 + row;
      if (un) {
        const f32x4* Ep = (const f32x4*)(E + (size_t)parents[2 * gr] * H);
#pragma unroll
        for (int i = 0; i < 8; ++i) *(f32x4*)&Cb[row][(cc + i) * 4] = Ep[cc + i];
      } else {
        const f32x4* Ep0 = (const f32x4*)(E + (size_t)parents[2 * gr] * H);
        const f32x4* Ep1 = (const f32x4*)(E + (size_t)parents[2 * gr + 1] * H);
#pragma unroll
        for (int i = 0; i < 8; ++i) *(f32x4*)&Sb[row][(cc + i) * 4] = Ep0[cc + i];
#pragma unroll
        for (int i = 0; i < 8; ++i) *(f32x4*)&Cb[row][(cc + i) * 4] = Ep1[cc + i];
      }
    }
  }
  __syncthreads();

  f32x4 acc[4][4];

  // ---- redux chain (5 linears) ----
  if (un) {
    zero_acc(acc);
    gemm_pass(acc, Cb, frags, SLOT_MPU(0), 4, 0, wr, wc, lane);
    __syncthreads();
    epilogue(acc, mpu_b, Cb, Sb, 0, nullptr, wr, wc, lane);
    __syncthreads();
#pragma unroll
    for (int l = 1; l <= 3; ++l) {
      zero_acc(acc);
      gemm_pass(acc, (l == 1) ? Cb : Sb, frags, SLOT_MPU(l), 4, 0, wr, wc, lane);
      __syncthreads();
      epilogue(acc, mpu_b + l * H, Cb, Sb, 1, nullptr, wr, wc, lane);
      __syncthreads();
    }
    zero_acc(acc);
    gemm_pass(acc, Sb, frags, SLOT_MPU(4), 4, 0, wr, wc, lane);
    __syncthreads();
    epilogue(acc, mpu_b + 4 * H, Cb, Sb, 0, nullptr, wr, wc, lane);
    __syncthreads();
  } else {
    zero_acc(acc);
    gemm_pass(acc, Sb, frags, SLOT_MPB0, 8, 0, wr, wc, lane);  // k = 0..127   (E[p0])
    gemm_pass(acc, Cb, frags, SLOT_MPB0, 8, 4, wr, wc, lane);  // k = 128..255 (E[p1])
    __syncthreads();
    epilogue(acc, mpb0_b, Cb, Sb, 0, nullptr, wr, wc, lane);
    __syncthreads();
#pragma unroll
    for (int l = 1; l <= 3; ++l) {
      zero_acc(acc);
      gemm_pass(acc, (l == 1) ? Cb : Sb, frags, SLOT_MPB(l - 1), 4, 0, wr, wc, lane);
      __syncthreads();
      epilogue(acc, mpb_b + (l - 1) * H, Cb, Sb, 1, nullptr, wr, wc, lane);
      __syncthreads();
    }
    zero_acc(acc);
    gemm_pass(acc, Sb, frags, SLOT_MPB(3), 4, 0, wr, wc, lane);
    __syncthreads();
    epilogue(acc, mpb_b + 3 * H, Cb, Sb, 0, nullptr, wr, wc, lane);
    __syncthreads();
  }

  // ---- stage base rows (E holds base for this layer, not yet overwritten) ----
  {
    int r4 = tid >> 2;
    int cc = (tid & 3) * 8;
#pragma unroll
    for (int rep = 0; rep < 2; ++rep) {
      int row = rep * 64 + r4;
      const f32x4* Ep = (const f32x4*)(E + (size_t)(s + row0 + row) * H);
#pragma unroll
      for (int i = 0; i < 8; ++i) *(f32x4*)&Sb[row][(cc + i) * 4] = Ep[cc + i];
    }
  }
  __syncthreads();

  // ---- node chain (5 linears, first K=256 on [base | redux]) ----
  zero_acc(acc);
  gemm_pass(acc, Sb, frags, SLOT_NE0, 8, 0, wr, wc, lane);  // base half
  gemm_pass(acc, Cb, frags, SLOT_NE0, 8, 4, wr, wc, lane);  // redux half
  __syncthreads();
  epilogue(acc, ne0_b, Cb, Sb, 0, nullptr, wr, wc, lane);
  __syncthreads();
#pragma unroll
  for (int l = 1; l <= 3; ++l) {
    zero_acc(acc);
    gemm_pass(acc, (l == 1) ? Cb : Sb, frags, SLOT_NE(l - 1), 4, 0, wr, wc, lane);
    __syncthreads();
    epilogue(acc, ne_b + (l - 1) * H, Cb, Sb, 1, nullptr, wr, wc, lane);
    __syncthreads();
  }
  zero_acc(acc);
  gemm_pass(acc, Sb, frags, SLOT_NE(3), 4, 0, wr, wc, lane);
  epilogue(acc, ne_b + 3 * H, Cb, Sb, 2, E + (size_t)(s + row0) * H, wr, wc, lane);
}

// ---------------------------------------------------------------------------
extern "C" void kernel_launch(void* const* d_in, const int* in_sizes, int n_in,
                              void* d_out, int out_size, void* d_ws, size_t ws_size,
                              hipStream_t stream) {
  const float* node_feats = (const float*)d_in[0];
  const float* emb_w  = (const float*)d_in[1];
  const float* emb_b  = (const float*)d_in[2];
  const float* ne0_w  = (const float*)d_in[3];
  const float* ne0_b  = (const float*)d_in[4];
  const float* ne_w   = (const float*)d_in[5];
  const float* ne_b   = (const float*)d_in[6];
  const float* mpu_w  = (const float*)d_in[7];
  const float* mpu_b  = (const float*)d_in[8];
  const float* mpb0_w = (const float*)d_in[9];
  const float* mpb0_b = (const float*)d_in[10];
  const float* mpb_w  = (const float*)d_in[11];
  const float* mpb_b  = (const float*)d_in[12];
  const int*   parents = (const int*)d_in[13];
  float* E = (float*)d_out;
  __bf16* frags = (__bf16*)d_ws;   // needs 544*2048 B ~= 1.1 MB

  prep_kernel<<<(TOTAL_FP + 3) / 4, 256, 0, stream>>>(frags, mpu_w, mpb0_w, mpb_w, ne0_w, ne_w);
  embed_kernel<<<N_TOTAL / 64, 256, 0, stream>>>(E, node_feats, emb_w, emb_b);
  for (int l = 1; l < L_LAYERS; ++l) {
    phase_kernel<<<M_NODES / 128, 256, 0, stream>>>(E, parents, frags, mpu_b, mpb0_b, mpb_b,
                                                    ne0_b, ne_b, l * M_NODES);
  }
}